// Round 2
// baseline (643.783 us; speedup 1.0000x reference)
//
#include <hip/hip_runtime.h>
#include <hip/hip_bf16.h>
#include <math.h>

// PNA forward, restructured:
//   C  = x @ W_pre[0:128]   + b_pre        [N,128]  (dst-side, per node)
//   P2 = x @ W_pre[128:256]                [N,128]  (src-side, per node)
//   per dst node i with c = C[i]: h_e = c + P2[src_e]
//     mean = c + m1, max = c + max(P2), min = c + min(P2),
//     var  = m2 - m1^2 (shift invariant), std = sqrt(var + 1e-5)
//   agg scaled by deg/16 (avg_deg = E/N = 16 exactly)
//   out = relu((concat(x, agg) @ W_post + b_post) @ W_lin + b_lin)

#define F 128

// ---------------- generic tiled f32 GEMM: out[N,128] = concat(A1[:,128],A2) @ W[KTOT,128] + bias ----------------
template<int KTOT, bool HASB, bool RELU>
__global__ __launch_bounds__(256) void gemm_k(
    const float* __restrict__ A1, const float* __restrict__ A2,
    const float* __restrict__ W, const float* __restrict__ bias,
    float* __restrict__ out, int N)
{
  __shared__ float lds[64][128];
  const int tid = threadIdx.x;
  const int cg  = tid & 63;   // owns cols cg, cg+64
  const int rg  = tid >> 6;   // rows rg*16 .. +15
  const int rowBase = blockIdx.x * 64;

  float acc0[16], acc1[16];
#pragma unroll
  for (int i = 0; i < 16; ++i) { acc0[i] = 0.f; acc1[i] = 0.f; }

  const int nChunk = KTOT / 128;
  for (int kc = 0; kc < nChunk; ++kc) {
    const float* src; int ld; int kofs;
    if (kc == 0) { src = A1; ld = 128; kofs = 0; }
    else         { src = A2; ld = KTOT - 128; kofs = (kc - 1) * 128; }
    __syncthreads();
#pragma unroll
    for (int i = 0; i < 8; ++i) {
      int q  = tid + 256 * i;       // 0..2047 float4 slots
      int r  = q >> 5;
      int cv = (q & 31) * 4;
      int gr = rowBase + r;
      float4 v = make_float4(0.f, 0.f, 0.f, 0.f);
      if (gr < N) v = *reinterpret_cast<const float4*>(&src[(size_t)gr * ld + kofs + cv]);
      *reinterpret_cast<float4*>(&lds[r][cv]) = v;
    }
    __syncthreads();
    const float* Wc = W + (size_t)kc * 128 * 128;
#pragma unroll 8
    for (int k4 = 0; k4 < 32; ++k4) {
      float w00 = Wc[(k4 * 4 + 0) * 128 + cg];
      float w01 = Wc[(k4 * 4 + 0) * 128 + cg + 64];
      float w10 = Wc[(k4 * 4 + 1) * 128 + cg];
      float w11 = Wc[(k4 * 4 + 1) * 128 + cg + 64];
      float w20 = Wc[(k4 * 4 + 2) * 128 + cg];
      float w21 = Wc[(k4 * 4 + 2) * 128 + cg + 64];
      float w30 = Wc[(k4 * 4 + 3) * 128 + cg];
      float w31 = Wc[(k4 * 4 + 3) * 128 + cg + 64];
#pragma unroll
      for (int rr = 0; rr < 16; ++rr) {
        float4 a = *reinterpret_cast<const float4*>(&lds[rg * 16 + rr][k4 * 4]);
        acc0[rr] += a.x * w00 + a.y * w10 + a.z * w20 + a.w * w30;
        acc1[rr] += a.x * w01 + a.y * w11 + a.z * w21 + a.w * w31;
      }
    }
  }
  float b0 = HASB ? bias[cg] : 0.f;
  float b1 = HASB ? bias[cg + 64] : 0.f;
#pragma unroll
  for (int rr = 0; rr < 16; ++rr) {
    int gr = rowBase + rg * 16 + rr;
    if (gr < N) {
      float v0 = acc0[rr] + b0;
      float v1 = acc1[rr] + b1;
      if (RELU) { v0 = fmaxf(v0, 0.f); v1 = fmaxf(v1, 0.f); }
      out[(size_t)gr * 128 + cg]      = v0;
      out[(size_t)gr * 128 + cg + 64] = v1;
    }
  }
}

// ---------------- CSR build ----------------
__global__ void zero_k(int* __restrict__ p, int n) {
  int i = blockIdx.x * 256 + threadIdx.x;
  if (i < n) p[i] = 0;
}

__global__ void count_k(const int* __restrict__ ei, int* __restrict__ deg, int E) {
  int e = blockIdx.x * 256 + threadIdx.x;
  if (e < E) atomicAdd(&deg[ei[E + e]], 1);
}

__global__ __launch_bounds__(1024) void scan_k(const int* __restrict__ deg,
                                               int* __restrict__ offs,
                                               int* __restrict__ cursor, int n) {
  __shared__ int wtot[16];
  __shared__ int base_s;
  int tid = threadIdx.x;
  int lane = tid & 63, wid = tid >> 6;
  if (tid == 0) base_s = 0;
  __syncthreads();
  for (int start = 0; start < n; start += 1024) {
    int i = start + tid;
    int v = (i < n) ? deg[i] : 0;
    int x = v;
#pragma unroll
    for (int d = 1; d < 64; d <<= 1) {
      int y = __shfl_up(x, d);
      if (lane >= d) x += y;
    }
    if (lane == 63) wtot[wid] = x;
    __syncthreads();
    if (wid == 0) {
      int t = (lane < 16) ? wtot[lane] : 0;
      int xx = t;
#pragma unroll
      for (int d = 1; d < 16; d <<= 1) {
        int y = __shfl_up(xx, d);
        if (lane >= d) xx += y;
      }
      if (lane < 16) wtot[lane] = xx - t;  // exclusive
    }
    __syncthreads();
    int excl = base_s + wtot[wid] + (x - v);
    if (i < n) { offs[i] = excl; cursor[i] = excl; }
    __syncthreads();
    if (tid == 1023) base_s = excl + v;
    __syncthreads();
  }
  if (tid == 0) offs[n] = base_s;
}

__global__ void scatter_k(const int* __restrict__ ei, int* __restrict__ cursor,
                          int* __restrict__ ssrc, int E) {
  int e = blockIdx.x * 256 + threadIdx.x;
  if (e < E) {
    int d = ei[E + e];
    int pos = atomicAdd(&cursor[d], 1);
    ssrc[pos] = ei[e];
  }
}

// ---------------- aggregation: one block per node ----------------
__global__ __launch_bounds__(128) void agg_k(
    const float* __restrict__ P2, const float* __restrict__ C,
    const int* __restrict__ offs, const int* __restrict__ ssrc,
    float* __restrict__ AGG, int N)
{
  __shared__ int sidx[128];
  int i = blockIdx.x;
  int f = threadIdx.x;
  int start = offs[i], end = offs[i + 1];
  int deg = end - start;
  float sum = 0.f, sq = 0.f, mx = -INFINITY, mn = INFINITY;
  for (int base = start; base < end; base += 128) {
    int cnt = min(end - base, 128);
    __syncthreads();
    if (f < cnt) sidx[f] = ssrc[base + f];
    __syncthreads();
    for (int j = 0; j < cnt; ++j) {
      float v = P2[(size_t)sidx[j] * 128 + f];
      sum += v; sq += v * v; mx = fmaxf(mx, v); mn = fminf(mn, v);
    }
  }
  size_t o = (size_t)i * 512 + f;
  if (deg == 0) {
    AGG[o] = 0.f; AGG[o + 128] = 0.f; AGG[o + 256] = 0.f; AGG[o + 384] = 0.f;
  } else {
    float c = C[(size_t)i * 128 + f];
    float degf = (float)deg;
    float m1 = sum / degf, m2 = sq / degf;
    float var = fmaxf(m2 - m1 * m1, 0.f);
    float sd = sqrtf(var + 1e-5f);
    float sc = degf * (1.0f / 16.0f);     // linear scaler: deg / avg_deg, avg_deg = 16 exactly
    AGG[o]       = (c + m1) * sc;
    AGG[o + 128] = (c + mx) * sc;
    AGG[o + 256] = (c + mn) * sc;
    AGG[o + 384] = sd * sc;
  }
}

extern "C" void kernel_launch(void* const* d_in, const int* in_sizes, int n_in,
                              void* d_out, int out_size, void* d_ws, size_t ws_size,
                              hipStream_t stream) {
  const float* x      = (const float*)d_in[0];
  const float* W_pre  = (const float*)d_in[1];
  const float* b_pre  = (const float*)d_in[2];
  const float* W_post = (const float*)d_in[3];
  const float* b_post = (const float*)d_in[4];
  const float* W_lin  = (const float*)d_in[5];
  const float* b_lin  = (const float*)d_in[6];
  const int*   ei     = (const int*)d_in[7];

  const int N = in_sizes[0] / 128;
  const int E = in_sizes[7] / 2;

  // workspace layout
  char* ws = (char*)d_ws;
  const size_t NB = (size_t)N * 128 * sizeof(float);   // 25.6 MB
  float* P2   = (float*)(ws);
  float* Cbuf = (float*)(ws + NB);            // C, later reused as T1
  float* AGG  = (float*)(ws + 2 * NB);        // N x 512
  int*   ssrc = (int*)(ws + 6 * NB);
  int*   deg  = ssrc + E;
  int*   offs = deg + N;
  int*   cur  = offs + N + 1;

  const int gRows = (N + 63) / 64;
  const int gE    = (E + 255) / 256;
  const int gN    = (N + 255) / 256;

  zero_k<<<gN, 256, 0, stream>>>(deg, N);
  // node-side GEMMs
  gemm_k<128, true,  false><<<gRows, 256, 0, stream>>>(x, nullptr, W_pre,            b_pre, Cbuf, N);
  gemm_k<128, false, false><<<gRows, 256, 0, stream>>>(x, nullptr, W_pre + 128*128, nullptr, P2,  N);
  // CSR build by dst
  count_k<<<gE, 256, 0, stream>>>(ei, deg, E);
  scan_k<<<1, 1024, 0, stream>>>(deg, offs, cur, N);
  scatter_k<<<gE, 256, 0, stream>>>(ei, cur, ssrc, E);
  // aggregation
  agg_k<<<N, 128, 0, stream>>>(P2, Cbuf, offs, ssrc, AGG, N);
  // post MLP (T1 reuses Cbuf)
  gemm_k<640, true, false><<<gRows, 256, 0, stream>>>(x, AGG, W_post, b_post, Cbuf, N);
  gemm_k<128, true, true ><<<gRows, 256, 0, stream>>>(Cbuf, nullptr, W_lin, b_lin, (float*)d_out, N);
}

// Round 3
// 434.301 us; speedup vs baseline: 1.4823x; 1.4823x over previous
//
#include <hip/hip_runtime.h>
#include <hip/hip_bf16.h>
#include <math.h>

// PNA forward, restructured (round 3: GEMMs on f16 MFMA):
//   C  = x @ W_pre[0:128]   + b_pre   [N,128] f32
//   P2 = x @ W_pre[128:256]           [N,128] f32
//   per dst i, c = C[i]: mean=c+m1, max=c+max(P2), min=c+min(P2), var shift-invariant
//   AGG (f16) = [mean,max,min,std] * deg/16
//   T1 (f16)  = concat(x, AGG) @ W_post + b_post
//   out (f32) = relu(T1 @ W_lin + b_lin)

typedef _Float16 f16;
typedef _Float16 f16x8 __attribute__((ext_vector_type(8)));
typedef float    f32x4 __attribute__((ext_vector_type(4)));

// ---------------- MFMA GEMM: out[M,128] = concat(A1[:,KO1], A2) @ Wt^T + bias ----------------
// A1,A2: f16 row-major (ld KO1 / KTOT-KO1). Wt: f16 [128][KTOT] (transposed weights).
// Block: 256 thr / 4 waves (2x2), tile 128 rows x 128 cols, wave tile 64x64, BK=32.
template<int KTOT, int KO1, bool HASB, bool RELU, bool OUTF16>
__global__ __launch_bounds__(256) void gemm_mfma_k(
    const f16* __restrict__ A1, const f16* __restrict__ A2,
    const f16* __restrict__ Wt, const float* __restrict__ bias,
    float* __restrict__ outF, f16* __restrict__ outH, int M)
{
  __shared__ __align__(16) f16 Asm[4][128][8];   // [kgrp][row][8]  8KB
  __shared__ __align__(16) f16 Bsm[4][128][8];   // [kgrp][col][8]  8KB
  const int tid = threadIdx.x;
  const int l   = tid & 63;
  const int w   = tid >> 6;
  const int wr  = (w >> 1) * 64;     // wave row offset in tile
  const int wc  = (w & 1) * 64;      // wave col offset
  const int rowBase = blockIdx.x * 128;

  f32x4 acc[4][4];
#pragma unroll
  for (int r = 0; r < 4; ++r)
#pragma unroll
    for (int c = 0; c < 4; ++c) acc[r][c] = (f32x4){0.f, 0.f, 0.f, 0.f};

  constexpr int NSTEP = KTOT / 32;
  const int ld2 = KTOT - KO1;

  // staging: 1024 16B-slots: [0,512) = A (kgrp=s>>7, row=s&127), [512,1024) = B (kgrp, col)
  float4 st[4];
  auto loadStep = [&](int k0) {
#pragma unroll
    for (int i = 0; i < 2; ++i) {           // A slots
      int s = tid + 256 * i;
      int kg = s >> 7, rr = s & 127;
      int grow = rowBase + rr; if (grow > M - 1) grow = M - 1;
      int k = k0 + kg * 8;
      const f16* src = (k < KO1) ? (A1 + (size_t)grow * KO1 + k)
                                 : (A2 + (size_t)grow * ld2 + (k - KO1));
      st[i] = *reinterpret_cast<const float4*>(src);
    }
#pragma unroll
    for (int i = 0; i < 2; ++i) {           // B slots
      int s = tid + 256 * i;
      int kg = s >> 7, cc = s & 127;
      st[2 + i] = *reinterpret_cast<const float4*>(Wt + (size_t)cc * KTOT + k0 + kg * 8);
    }
  };

  loadStep(0);
  const int kg = l >> 4, li = l & 15;
  for (int t = 0; t < NSTEP; ++t) {
    __syncthreads();   // previous compute done, LDS reusable
    reinterpret_cast<float4*>(&Asm[0][0][0])[tid]       = st[0];
    reinterpret_cast<float4*>(&Asm[0][0][0])[tid + 256] = st[1];
    reinterpret_cast<float4*>(&Bsm[0][0][0])[tid]       = st[2];
    reinterpret_cast<float4*>(&Bsm[0][0][0])[tid + 256] = st[3];
    __syncthreads();
    if (t + 1 < NSTEP) loadStep((t + 1) * 32);   // prefetch under compute

    f16x8 a[4], b[4];
#pragma unroll
    for (int r = 0; r < 4; ++r)
      a[r] = *reinterpret_cast<const f16x8*>(&Asm[kg][wr + r * 16 + li][0]);
#pragma unroll
    for (int c = 0; c < 4; ++c)
      b[c] = *reinterpret_cast<const f16x8*>(&Bsm[kg][wc + c * 16 + li][0]);
#pragma unroll
    for (int r = 0; r < 4; ++r)
#pragma unroll
      for (int c = 0; c < 4; ++c)
        acc[r][c] = __builtin_amdgcn_mfma_f32_16x16x32_f16(a[r], b[c], acc[r][c], 0, 0, 0);
  }

  // epilogue: C/D layout col = l&15, row = (l>>4)*4 + j  [HW-verified]
#pragma unroll
  for (int c = 0; c < 4; ++c) {
    int col = wc + c * 16 + li;
    float bv = HASB ? bias[col] : 0.f;
#pragma unroll
    for (int r = 0; r < 4; ++r) {
#pragma unroll
      for (int j = 0; j < 4; ++j) {
        int row = rowBase + wr + r * 16 + kg * 4 + j;
        if (row < M) {
          float v = acc[r][c][j] + bv;
          if (RELU) v = fmaxf(v, 0.f);
          if (OUTF16) outH[(size_t)row * 128 + col] = (f16)v;
          else        outF[(size_t)row * 128 + col] = v;
        }
      }
    }
  }
}

// ---------------- conversions ----------------
__global__ void cvt_x_k(const float* __restrict__ x, f16* __restrict__ xf, int n) {
  int i = (blockIdx.x * 256 + threadIdx.x) * 4;
  if (i < n) {
    float4 v = *reinterpret_cast<const float4*>(&x[i]);
    xf[i] = (f16)v.x; xf[i + 1] = (f16)v.y; xf[i + 2] = (f16)v.z; xf[i + 3] = (f16)v.w;
  }
}

// W [K][128] -> Wt f16 [128][K]
__global__ void transp_w_k(const float* __restrict__ W, f16* __restrict__ Wt, int K) {
  int e = blockIdx.x * 256 + threadIdx.x;
  if (e < 128 * K) {
    int nn = e / K, kk = e - nn * K;
    Wt[e] = (f16)W[(size_t)kk * 128 + nn];
  }
}

// ---------------- CSR build ----------------
__global__ void zero_k(int* __restrict__ p, int n) {
  int i = blockIdx.x * 256 + threadIdx.x;
  if (i < n) p[i] = 0;
}

__global__ void count_k(const int* __restrict__ ei, int* __restrict__ deg, int E) {
  int e = blockIdx.x * 256 + threadIdx.x;
  if (e < E) atomicAdd(&deg[ei[E + e]], 1);
}

__global__ __launch_bounds__(1024) void scan_k(const int* __restrict__ deg,
                                               int* __restrict__ offs,
                                               int* __restrict__ cursor, int n) {
  __shared__ int wtot[16];
  __shared__ int base_s;
  int tid = threadIdx.x;
  int lane = tid & 63, wid = tid >> 6;
  if (tid == 0) base_s = 0;
  __syncthreads();
  for (int start = 0; start < n; start += 1024) {
    int i = start + tid;
    int v = (i < n) ? deg[i] : 0;
    int x = v;
#pragma unroll
    for (int d = 1; d < 64; d <<= 1) {
      int y = __shfl_up(x, d);
      if (lane >= d) x += y;
    }
    if (lane == 63) wtot[wid] = x;
    __syncthreads();
    if (wid == 0) {
      int t = (lane < 16) ? wtot[lane] : 0;
      int xx = t;
#pragma unroll
      for (int d = 1; d < 16; d <<= 1) {
        int y = __shfl_up(xx, d);
        if (lane >= d) xx += y;
      }
      if (lane < 16) wtot[lane] = xx - t;  // exclusive
    }
    __syncthreads();
    int excl = base_s + wtot[wid] + (x - v);
    if (i < n) { offs[i] = excl; cursor[i] = excl; }
    __syncthreads();
    if (tid == 1023) base_s = excl + v;
    __syncthreads();
  }
  if (tid == 0) offs[n] = base_s;
}

__global__ void scatter_k(const int* __restrict__ ei, int* __restrict__ cursor,
                          int* __restrict__ ssrc, int E) {
  int e = blockIdx.x * 256 + threadIdx.x;
  if (e < E) {
    int d = ei[E + e];
    int pos = atomicAdd(&cursor[d], 1);
    ssrc[pos] = ei[e];
  }
}

// ---------------- aggregation: one block per node, writes f16 AGG ----------------
__global__ __launch_bounds__(128) void agg_k(
    const float* __restrict__ P2, const float* __restrict__ C,
    const int* __restrict__ offs, const int* __restrict__ ssrc,
    f16* __restrict__ AGG, int N)
{
  __shared__ int sidx[128];
  int i = blockIdx.x;
  int f = threadIdx.x;
  int start = offs[i], end = offs[i + 1];
  int deg = end - start;
  float sum = 0.f, sq = 0.f, mx = -INFINITY, mn = INFINITY;
  for (int base = start; base < end; base += 128) {
    int cnt = min(end - base, 128);
    __syncthreads();
    if (f < cnt) sidx[f] = ssrc[base + f];
    __syncthreads();
    for (int j = 0; j < cnt; ++j) {
      float v = P2[(size_t)sidx[j] * 128 + f];
      sum += v; sq += v * v; mx = fmaxf(mx, v); mn = fminf(mn, v);
    }
  }
  size_t o = (size_t)i * 512 + f;
  if (deg == 0) {
    AGG[o] = (f16)0.f; AGG[o + 128] = (f16)0.f; AGG[o + 256] = (f16)0.f; AGG[o + 384] = (f16)0.f;
  } else {
    float c = C[(size_t)i * 128 + f];
    float degf = (float)deg;
    float m1 = sum / degf, m2 = sq / degf;
    float var = fmaxf(m2 - m1 * m1, 0.f);
    float sd = sqrtf(var + 1e-5f);
    float sc = degf * (1.0f / 16.0f);     // deg / avg_deg, avg_deg = E/N = 16 exactly
    AGG[o]       = (f16)((c + m1) * sc);
    AGG[o + 128] = (f16)((c + mx) * sc);
    AGG[o + 256] = (f16)((c + mn) * sc);
    AGG[o + 384] = (f16)(sd * sc);
  }
}

extern "C" void kernel_launch(void* const* d_in, const int* in_sizes, int n_in,
                              void* d_out, int out_size, void* d_ws, size_t ws_size,
                              hipStream_t stream) {
  const float* x      = (const float*)d_in[0];
  const float* W_pre  = (const float*)d_in[1];
  const float* b_pre  = (const float*)d_in[2];
  const float* W_post = (const float*)d_in[3];
  const float* b_post = (const float*)d_in[4];
  const float* W_lin  = (const float*)d_in[5];
  const float* b_lin  = (const float*)d_in[6];
  const int*   ei     = (const int*)d_in[7];

  const int N = in_sizes[0] / 128;
  const int E = in_sizes[7] / 2;

  // workspace layout
  char* ws = (char*)d_ws;
  size_t off = 0;
  auto alloc = [&](size_t bytes) -> void* {
    void* p = ws + off; off += (bytes + 255) & ~(size_t)255; return p;
  };
  f16*   xf     = (f16*)  alloc((size_t)N * 128 * 2);
  float* Cbuf   = (float*)alloc((size_t)N * 128 * 4);
  float* P2     = (float*)alloc((size_t)N * 128 * 4);
  f16*   AGG    = (f16*)  alloc((size_t)N * 512 * 2);
  f16*   T1     = (f16*)  alloc((size_t)N * 128 * 2);
  f16*   WtPreT = (f16*)  alloc(128 * 128 * 2);
  f16*   WtPreB = (f16*)  alloc(128 * 128 * 2);
  f16*   WtPost = (f16*)  alloc(128 * 640 * 2);
  f16*   WtLin  = (f16*)  alloc(128 * 128 * 2);
  int*   ssrc   = (int*)  alloc((size_t)E * 4);
  int*   deg    = (int*)  alloc((size_t)N * 4);
  int*   offs   = (int*)  alloc((size_t)(N + 1) * 4);
  int*   cur    = (int*)  alloc((size_t)N * 4);

  const int gTile = (N + 127) / 128;
  const int gE    = (E + 255) / 256;
  const int gN    = (N + 255) / 256;

  // conversions
  cvt_x_k<<<(N * 128 / 4 + 255) / 256, 256, 0, stream>>>(x, xf, N * 128);
  transp_w_k<<<(128 * 128 + 255) / 256, 256, 0, stream>>>(W_pre,             WtPreT, 128);
  transp_w_k<<<(128 * 128 + 255) / 256, 256, 0, stream>>>(W_pre + 128 * 128, WtPreB, 128);
  transp_w_k<<<(128 * 640 + 255) / 256, 256, 0, stream>>>(W_post,            WtPost, 640);
  transp_w_k<<<(128 * 128 + 255) / 256, 256, 0, stream>>>(W_lin,             WtLin,  128);

  zero_k<<<gN, 256, 0, stream>>>(deg, N);

  // node-side GEMMs (f16 MFMA, f32 out)
  gemm_mfma_k<128, 128, true,  false, false><<<gTile, 256, 0, stream>>>(xf, nullptr, WtPreT, b_pre, Cbuf, nullptr, N);
  gemm_mfma_k<128, 128, false, false, false><<<gTile, 256, 0, stream>>>(xf, nullptr, WtPreB, nullptr, P2, nullptr, N);

  // CSR build by dst
  count_k<<<gE, 256, 0, stream>>>(ei, deg, E);
  scan_k<<<1, 1024, 0, stream>>>(deg, offs, cur, N);
  scatter_k<<<gE, 256, 0, stream>>>(ei, cur, ssrc, E);

  // aggregation -> AGG f16 [N][512]
  agg_k<<<N, 128, 0, stream>>>(P2, Cbuf, offs, ssrc, AGG, N);

  // post MLP: T1 = concat(x, AGG) @ W_post + b_post   (f16 out)
  gemm_mfma_k<640, 128, true, false, true><<<gTile, 256, 0, stream>>>(xf, AGG, WtPost, b_post, nullptr, T1, N);
  // final: out = relu(T1 @ W_lin + b_lin)   (f32 out)
  gemm_mfma_k<128, 128, true, true, false><<<gTile, 256, 0, stream>>>(T1, nullptr, WtLin, b_lin, (float*)d_out, nullptr, N);
}

// Round 4
// 413.428 us; speedup vs baseline: 1.5572x; 1.0505x over previous
//
#include <hip/hip_runtime.h>
#include <hip/hip_bf16.h>
#include <math.h>

// PNA forward (round 4):
//   CP = x @ [W_preT | W_preB] + [b_pre|0]   f16 [N][256]  (C | P2)
//   per dst i: h_e = C[i] + P2[src]; mean/max/min shift by c, var shift-invariant
//   AGG f16 [N][512] = [mean,max,min,std] * deg/16   (avg_deg = E/N = 16 exactly)
//   T1  f16 = concat(x, AGG) @ W_post + b_post
//   out f32 = relu(T1 @ W_lin + b_lin)

typedef _Float16 f16;
typedef _Float16 f16x8 __attribute__((ext_vector_type(8)));
typedef _Float16 f16x2 __attribute__((ext_vector_type(2)));
typedef float    f32x4 __attribute__((ext_vector_type(4)));

__device__ __forceinline__ unsigned packh2(float a, float b) {
  union { unsigned u; f16x2 h; } x; x.h = (f16x2){(f16)a, (f16)b}; return x.u;
}
__device__ __forceinline__ float2 unpackh2(unsigned v) {
  union { unsigned u; f16x2 h; } x; x.u = v;
  return make_float2((float)x.h.x, (float)x.h.y);
}

// ---------------- MFMA GEMM ----------------
// out[M, gridDim.y*128] = concat(A1[:,KO1], A2) @ Wt^T + bias
// Wt: f16 [NCOLS][KTOT] transposed weights. Block: 256 thr / 4 waves (2x2),
// tile 64 rows x 128 cols (col tile via blockIdx.y), wave tile 32x64, BK=32.
template<int KTOT, int KO1, bool HASB, bool RELU, bool OUTF16>
__global__ __launch_bounds__(256) void gemm_mfma_k(
    const f16* __restrict__ A1, const f16* __restrict__ A2,
    const f16* __restrict__ Wt, const float* __restrict__ bias,
    float* __restrict__ outF, f16* __restrict__ outH, int M, int ldOut)
{
  __shared__ __align__(16) f16 Asm[4][64][8];    // 4 KB
  __shared__ __align__(16) f16 Bsm[4][128][8];   // 8 KB
  const int tid = threadIdx.x;
  const int l   = tid & 63;
  const int w   = tid >> 6;
  const int wr  = (w >> 1) * 32;
  const int wc  = (w & 1) * 64;
  const int rowBase = blockIdx.x * 64;
  const int colBase = blockIdx.y * 128;

  f32x4 acc[2][4];
#pragma unroll
  for (int r = 0; r < 2; ++r)
#pragma unroll
    for (int c = 0; c < 4; ++c) acc[r][c] = (f32x4){0.f, 0.f, 0.f, 0.f};

  constexpr int NSTEP = KTOT / 32;
  constexpr int ld2 = (KTOT > KO1) ? (KTOT - KO1) : 1;

  float4 st[3];
  auto loadStep = [&](int k0) {
    {
      int kg = tid >> 6, rr = tid & 63;
      int grow = rowBase + rr; if (grow > M - 1) grow = M - 1;
      int k = k0 + kg * 8;
      const f16* src;
      if constexpr (KO1 == KTOT) src = A1 + (size_t)grow * KO1 + k;
      else src = (k < KO1) ? A1 + (size_t)grow * KO1 + k
                           : A2 + (size_t)grow * ld2 + (k - KO1);
      st[0] = *reinterpret_cast<const float4*>(src);
    }
#pragma unroll
    for (int i = 0; i < 2; ++i) {
      int q = tid + 256 * i;
      int kg = q >> 7, cc = q & 127;
      st[1 + i] = *reinterpret_cast<const float4*>(Wt + (size_t)(colBase + cc) * KTOT + k0 + kg * 8);
    }
  };

  loadStep(0);
  const int kg = l >> 4, li = l & 15;
  for (int t = 0; t < NSTEP; ++t) {
    __syncthreads();
    reinterpret_cast<float4*>(&Asm[0][0][0])[tid]       = st[0];
    reinterpret_cast<float4*>(&Bsm[0][0][0])[tid]       = st[1];
    reinterpret_cast<float4*>(&Bsm[0][0][0])[tid + 256] = st[2];
    __syncthreads();
    if (t + 1 < NSTEP) loadStep((t + 1) * 32);

    f16x8 a[2], b[4];
#pragma unroll
    for (int r = 0; r < 2; ++r)
      a[r] = *reinterpret_cast<const f16x8*>(&Asm[kg][wr + r * 16 + li][0]);
#pragma unroll
    for (int c = 0; c < 4; ++c)
      b[c] = *reinterpret_cast<const f16x8*>(&Bsm[kg][wc + c * 16 + li][0]);
#pragma unroll
    for (int r = 0; r < 2; ++r)
#pragma unroll
      for (int c = 0; c < 4; ++c)
        acc[r][c] = __builtin_amdgcn_mfma_f32_16x16x32_f16(a[r], b[c], acc[r][c], 0, 0, 0);
  }

  // C/D layout: col = l&15 (li), row = (l>>4)*4 + j   [HW-verified round 3]
#pragma unroll
  for (int c = 0; c < 4; ++c) {
    int col = colBase + wc + c * 16 + li;
    float bv = (HASB && col < 128) ? bias[col] : 0.f;
#pragma unroll
    for (int r = 0; r < 2; ++r) {
#pragma unroll
      for (int j = 0; j < 4; ++j) {
        int row = rowBase + wr + r * 16 + kg * 4 + j;
        if (row < M) {
          float v = acc[r][c][j] + bv;
          if (RELU) v = fmaxf(v, 0.f);
          if (OUTF16) outH[(size_t)row * ldOut + col] = (f16)v;
          else        outF[(size_t)row * ldOut + col] = v;
        }
      }
    }
  }
}

// ---------------- conversions ----------------
__global__ void cvt_x_k(const float* __restrict__ x, f16* __restrict__ xf, int n) {
  int i = (blockIdx.x * 256 + threadIdx.x) * 4;
  if (i < n) {
    float4 v = *reinterpret_cast<const float4*>(&x[i]);
    xf[i] = (f16)v.x; xf[i + 1] = (f16)v.y; xf[i + 2] = (f16)v.z; xf[i + 3] = (f16)v.w;
  }
}

// fused pre weight: Wt[256][128]; col n<128 -> W_pre[k][n] (C), n>=128 -> W_pre[128+k][n-128] (P2)
__global__ void prep_wpre_k(const float* __restrict__ W, f16* __restrict__ Wt) {
  int e = blockIdx.x * 256 + threadIdx.x;   // < 256*128
  if (e < 256 * 128) {
    int n = e >> 7, k = e & 127;
    float v = (n < 128) ? W[(size_t)k * 128 + n] : W[(size_t)(128 + k) * 128 + (n - 128)];
    Wt[e] = (f16)v;
  }
}

// generic: W [K][128] -> Wt f16 [128][K]
__global__ void transp_w_k(const float* __restrict__ W, f16* __restrict__ Wt, int K) {
  int e = blockIdx.x * 256 + threadIdx.x;
  if (e < 128 * K) {
    int nn = e / K, kk = e - nn * K;
    Wt[e] = (f16)W[(size_t)kk * 128 + nn];
  }
}

// ---------------- CSR build ----------------
__global__ void zero_k(int* __restrict__ p, int n) {
  int i = blockIdx.x * 256 + threadIdx.x;
  if (i < n) p[i] = 0;
}

__global__ void count_k(const int* __restrict__ ei, int* __restrict__ deg, int E) {
  int e = blockIdx.x * 256 + threadIdx.x;
  if (e < E) atomicAdd(&deg[ei[E + e]], 1);
}

__device__ __forceinline__ int blockExclScan(int v, int* wtot) {
  int lane = threadIdx.x & 63, wid = threadIdx.x >> 6;
  int x = v;
#pragma unroll
  for (int d = 1; d < 64; d <<= 1) {
    int y = __shfl_up(x, d);
    if (lane >= d) x += y;
  }
  if (lane == 63) wtot[wid] = x;
  __syncthreads();
  if (threadIdx.x == 0) {
    int s = 0;
#pragma unroll
    for (int k = 0; k < 4; ++k) { int t = wtot[k]; wtot[k] = s; s += t; }
  }
  __syncthreads();
  return wtot[wid] + x - v;   // exclusive
}

__global__ __launch_bounds__(256) void scan1_k(const int* __restrict__ deg,
                                               int* __restrict__ offs,
                                               int* __restrict__ partials, int n) {
  __shared__ int wtot[4];
  int i = blockIdx.x * 256 + threadIdx.x;
  int v = (i < n) ? deg[i] : 0;
  int e = blockExclScan(v, wtot);
  if (i < n) offs[i] = e;
  if (threadIdx.x == 255) partials[blockIdx.x] = e + v;
}

__global__ __launch_bounds__(256) void scan2_k(int* __restrict__ partials, int nb) {
  __shared__ int wtot[4];
  int v = (threadIdx.x < nb) ? partials[threadIdx.x] : 0;
  int e = blockExclScan(v, wtot);
  if (threadIdx.x < nb) partials[threadIdx.x] = e;
}

__global__ void scan3_k(const int* __restrict__ partials, int* __restrict__ offs,
                        int* __restrict__ cur, int n, int E) {
  int i = blockIdx.x * 256 + threadIdx.x;
  if (i < n) {
    int v = offs[i] + partials[i >> 8];
    offs[i] = v; cur[i] = v;
  }
  if (i == 0) offs[n] = E;
}

__global__ void scatter_k(const int* __restrict__ ei, int* __restrict__ cursor,
                          int* __restrict__ ssrc, int E) {
  int e = blockIdx.x * 256 + threadIdx.x;
  if (e < E) {
    int d = ei[E + e];
    int pos = atomicAdd(&cursor[d], 1);
    ssrc[pos] = ei[e];
  }
}

// ---------------- aggregation: one WAVE per node, lane t owns cols {2t,2t+1} ----------------
__global__ __launch_bounds__(256) void agg_k(
    const f16* __restrict__ CP, const int* __restrict__ offs,
    const int* __restrict__ ssrc, f16* __restrict__ AGG, int N)
{
  int w = threadIdx.x >> 6;
  int t = threadIdx.x & 63;
  int i = blockIdx.x * 4 + w;
  if (i >= N) return;
  int start = offs[i], end = offs[i + 1];
  int deg = end - start;
  unsigned* AGGu = (unsigned*)AGG;              // 256 uints per row
  size_t o = (size_t)i * 256 + t;
  if (deg == 0) {
    AGGu[o] = 0u; AGGu[o + 64] = 0u; AGGu[o + 128] = 0u; AGGu[o + 192] = 0u;
    return;
  }
  const unsigned* CPu = (const unsigned*)CP;    // 128 uints per row; P2 half at +64
  float s0 = 0.f, s1 = 0.f, q0 = 0.f, q1 = 0.f;
  float mx0 = -INFINITY, mx1 = -INFINITY, mn0 = INFINITY, mn1 = INFINITY;
  for (int base = start; base < end; base += 64) {
    int cnt = min(end - base, 64);
    int myidx = (base + t < end) ? ssrc[base + t] : 0;
    for (int j = 0; j < cnt; ++j) {
      int src = __shfl(myidx, j);
      float2 v = unpackh2(CPu[(size_t)src * 128 + 64 + t]);
      s0 += v.x; s1 += v.y;
      q0 += v.x * v.x; q1 += v.y * v.y;
      mx0 = fmaxf(mx0, v.x); mx1 = fmaxf(mx1, v.y);
      mn0 = fminf(mn0, v.x); mn1 = fminf(mn1, v.y);
    }
  }
  float2 c = unpackh2(CPu[(size_t)i * 128 + t]);
  float degf = (float)deg;
  float inv = 1.f / degf;
  float m10 = s0 * inv, m11 = s1 * inv;
  float var0 = fmaxf(q0 * inv - m10 * m10, 0.f);
  float var1 = fmaxf(q1 * inv - m11 * m11, 0.f);
  float sd0 = sqrtf(var0 + 1e-5f), sd1 = sqrtf(var1 + 1e-5f);
  float sc = degf * (1.0f / 16.0f);             // deg / avg_deg, avg_deg = 16 exactly
  AGGu[o]       = packh2((c.x + m10) * sc, (c.y + m11) * sc);
  AGGu[o + 64]  = packh2((c.x + mx0) * sc, (c.y + mx1) * sc);
  AGGu[o + 128] = packh2((c.x + mn0) * sc, (c.y + mn1) * sc);
  AGGu[o + 192] = packh2(sd0 * sc, sd1 * sc);
}

extern "C" void kernel_launch(void* const* d_in, const int* in_sizes, int n_in,
                              void* d_out, int out_size, void* d_ws, size_t ws_size,
                              hipStream_t stream) {
  const float* x      = (const float*)d_in[0];
  const float* W_pre  = (const float*)d_in[1];
  const float* b_pre  = (const float*)d_in[2];
  const float* W_post = (const float*)d_in[3];
  const float* b_post = (const float*)d_in[4];
  const float* W_lin  = (const float*)d_in[5];
  const float* b_lin  = (const float*)d_in[6];
  const int*   ei     = (const int*)d_in[7];

  const int N = in_sizes[0] / 128;
  const int E = in_sizes[7] / 2;

  char* ws = (char*)d_ws;
  size_t off = 0;
  auto alloc = [&](size_t bytes) -> void* {
    void* p = ws + off; off += (bytes + 255) & ~(size_t)255; return p;
  };
  f16*   xf     = (f16*)  alloc((size_t)N * 128 * 2);
  f16*   CP     = (f16*)  alloc((size_t)N * 256 * 2);   // [C | P2]
  f16*   AGG    = (f16*)  alloc((size_t)N * 512 * 2);
  f16*   T1     = (f16*)  alloc((size_t)N * 128 * 2);
  f16*   WtPre  = (f16*)  alloc(256 * 128 * 2);
  f16*   WtPost = (f16*)  alloc(128 * 640 * 2);
  f16*   WtLin  = (f16*)  alloc(128 * 128 * 2);
  int*   ssrc   = (int*)  alloc((size_t)E * 4);
  int*   deg    = (int*)  alloc((size_t)N * 4);
  int*   offs   = (int*)  alloc((size_t)(N + 1) * 4);
  int*   cur    = (int*)  alloc((size_t)N * 4);
  int*   parts  = (int*)  alloc(1024 * 4);

  const int gTile = (N + 63) / 64;          // 782
  const int gE    = (E + 255) / 256;
  const int gN    = (N + 255) / 256;        // 196 (scan blocks)

  // conversions / weight prep
  cvt_x_k<<<(N * 128 / 4 + 255) / 256, 256, 0, stream>>>(x, xf, N * 128);
  prep_wpre_k<<<(256 * 128 + 255) / 256, 256, 0, stream>>>(W_pre, WtPre);
  transp_w_k<<<(128 * 640 + 255) / 256, 256, 0, stream>>>(W_post, WtPost, 640);
  transp_w_k<<<(128 * 128 + 255) / 256, 256, 0, stream>>>(W_lin,  WtLin,  128);

  zero_k<<<gN, 256, 0, stream>>>(deg, N);

  // fused pre GEMM: CP[N][256] = x @ [WpreT|WpreB]  (bias only on first 128 cols)
  gemm_mfma_k<128, 128, true, false, true><<<dim3(gTile, 2), 256, 0, stream>>>(
      xf, nullptr, WtPre, b_pre, nullptr, CP, N, 256);

  // CSR build by dst
  count_k<<<gE, 256, 0, stream>>>(ei, deg, E);
  scan1_k<<<gN, 256, 0, stream>>>(deg, offs, parts, N);
  scan2_k<<<1, 256, 0, stream>>>(parts, gN);
  scan3_k<<<gN, 256, 0, stream>>>(parts, offs, cur, N, E);
  scatter_k<<<gE, 256, 0, stream>>>(ei, cur, ssrc, E);

  // aggregation -> AGG f16 [N][512]
  agg_k<<<(N + 3) / 4, 256, 0, stream>>>(CP, offs, ssrc, AGG, N);

  // post MLP: T1 = concat(x, AGG) @ W_post + b_post   (f16 out)
  gemm_mfma_k<640, 128, true, false, true><<<dim3(gTile, 1), 256, 0, stream>>>(
      xf, AGG, WtPost, b_post, nullptr, T1, N, 128);
  // final: out = relu(T1 @ W_lin + b_lin)   (f32 out)
  gemm_mfma_k<128, 128, true, true, false><<<dim3(gTile, 1), 256, 0, stream>>>(
      T1, nullptr, WtLin, b_lin, (float*)d_out, nullptr, N, 128);
}

// Round 5
// 348.003 us; speedup vs baseline: 1.8499x; 1.1880x over previous
//
#include <hip/hip_runtime.h>
#include <hip/hip_bf16.h>
#include <math.h>

// PNA forward (round 5): barrier-free register-fragment MFMA GEMMs.
//   CP = x @ [W_preT | W_preB] + [b_pre|0]   f16 [N][256]  (C | P2)
//   per dst i: h_e = C[i] + P2[src]; mean/max/min shift by c, var shift-invariant
//   AGG f16 [N][512] = [mean,max,min,std] * deg/16   (avg_deg = E/N = 16 exactly)
//   T1  f16 = concat(x, AGG) @ W_post + b_post
//   out f32 = relu(T1 @ W_lin + b_lin)

typedef _Float16 f16;
typedef _Float16 f16x8 __attribute__((ext_vector_type(8)));
typedef _Float16 f16x2 __attribute__((ext_vector_type(2)));
typedef float    f32x4 __attribute__((ext_vector_type(4)));

__device__ __forceinline__ unsigned packh2(float a, float b) {
  union { unsigned u; f16x2 h; } x; x.h = (f16x2){(f16)a, (f16)b}; return x.u;
}
__device__ __forceinline__ float2 unpackh2(unsigned v) {
  union { unsigned u; f16x2 h; } x; x.u = v;
  return make_float2((float)x.h.x, (float)x.h.y);
}

// ---------------- register-fragment MFMA GEMM (no LDS staging, no K-loop barriers) ----------------
// out[M, *] = concat(A1[:,KO1], A2) @ Wt^T + bias.  Wt: f16 [NCOL][KTOT] (transposed weights).
// Block 256 thr / 4 waves; block tile 64 rows x 128 cols; wave tile 32x64 (2x4 16x16 frags).
// Fragments loaded straight global->VGPR (weights L2-resident; A rows L1/L2), 2-deep reg pipeline.
// LDS used only for the coalesced epilogue.
template<int KTOT, int KO1, bool HASB, bool RELU, bool OUTF16>
__global__ __launch_bounds__(256) void gemm_reg_k(
    const f16* __restrict__ A1, const f16* __restrict__ A2,
    const f16* __restrict__ Wt, const float* __restrict__ bias,
    float* __restrict__ outF, f16* __restrict__ outH, int M, int ldOut)
{
  const int tid = threadIdx.x;
  const int l   = tid & 63;
  const int w   = tid >> 6;
  const int wr  = (w >> 1) * 32;      // wave row offset in 64-row tile
  const int wc  = (w & 1) * 64;       // wave col offset in 128-col tile
  const int li  = l & 15, kg = l >> 4;
  const int rowBase = blockIdx.x * 64;
  const int colBase = blockIdx.y * 128;
  constexpr int ld2 = (KTOT > KO1) ? (KTOT - KO1) : 1;

  // per-lane fragment base offsets (32-bit; saddr-form global loads)
  int aOff[2], a2Off[2], bOff[4];
#pragma unroll
  for (int r = 0; r < 2; ++r) {
    int gr = rowBase + wr + r * 16 + li; if (gr > M - 1) gr = M - 1;
    aOff[r] = gr * KO1; a2Off[r] = gr * ld2;
  }
#pragma unroll
  for (int c = 0; c < 4; ++c) bOff[c] = (colBase + wc + c * 16 + li) * KTOT;

  f32x4 acc[2][4];
#pragma unroll
  for (int r = 0; r < 2; ++r)
#pragma unroll
    for (int c = 0; c < 4; ++c) acc[r][c] = (f32x4){0.f, 0.f, 0.f, 0.f};

  f16x8 aA[2], bA[4], aB[2], bB[4];
  auto lf = [&](int k0, f16x8 a[2], f16x8 b[4]) {
    int k = k0 + kg * 8;
    if (KO1 == KTOT || k0 < KO1) {      // wave-uniform branch (steps never straddle KO1)
#pragma unroll
      for (int r = 0; r < 2; ++r) a[r] = *reinterpret_cast<const f16x8*>(A1 + aOff[r] + k);
    } else {
#pragma unroll
      for (int r = 0; r < 2; ++r) a[r] = *reinterpret_cast<const f16x8*>(A2 + a2Off[r] + (k - KO1));
    }
#pragma unroll
    for (int c = 0; c < 4; ++c) b[c] = *reinterpret_cast<const f16x8*>(Wt + bOff[c] + k);
  };

  lf(0, aA, bA);
  for (int k0 = 0; k0 < KTOT; k0 += 64) {
    lf(k0 + 32, aB, bB);
#pragma unroll
    for (int r = 0; r < 2; ++r)
#pragma unroll
      for (int c = 0; c < 4; ++c)
        acc[r][c] = __builtin_amdgcn_mfma_f32_16x16x32_f16(aA[r], bA[c], acc[r][c], 0, 0, 0);
    if (k0 + 64 < KTOT) lf(k0 + 64, aA, bA);
#pragma unroll
    for (int r = 0; r < 2; ++r)
#pragma unroll
      for (int c = 0; c < 4; ++c)
        acc[r][c] = __builtin_amdgcn_mfma_f32_16x16x32_f16(aB[r], bB[c], acc[r][c], 0, 0, 0);
  }

  // bias (cols >=128 of the pre-GEMM's 256-wide output carry no bias)
  float bv[4];
#pragma unroll
  for (int c = 0; c < 4; ++c) {
    int col = colBase + wc + c * 16 + li;
    bv[c] = (HASB && col < 128) ? bias[col] : 0.f;
  }

  // epilogue: C/D layout col = li, row = kg*4 + j [HW-verified r3/r4]; LDS bounce -> coalesced stores
  if constexpr (OUTF16) {
    __shared__ __align__(16) f16 Ls[64][136];   // pad 8: kg-row bank shift 16 (2-way, free)
#pragma unroll
    for (int c = 0; c < 4; ++c) {
      int col = wc + c * 16 + li;
#pragma unroll
      for (int r = 0; r < 2; ++r)
#pragma unroll
        for (int j = 0; j < 4; ++j) {
          float v = acc[r][c][j] + bv[c];
          if (RELU) v = fmaxf(v, 0.f);
          Ls[wr + r * 16 + kg * 4 + j][col] = (f16)v;
        }
    }
    __syncthreads();
#pragma unroll
    for (int i = 0; i < 4; ++i) {
      int s = tid + 256 * i;              // 1024 slots of 16B (64 rows x 16)
      int rr = s >> 4, cc = (s & 15) * 8;
      int gr = rowBase + rr;
      if (gr < M)
        *reinterpret_cast<float4*>(&outH[(size_t)gr * ldOut + colBase + cc]) =
            *reinterpret_cast<const float4*>(&Ls[rr][cc]);
    }
  } else {
    __shared__ __align__(16) float Lf[64][132];  // pad 4: kg-row bank shift 16 (2-way, free)
#pragma unroll
    for (int c = 0; c < 4; ++c) {
      int col = wc + c * 16 + li;
#pragma unroll
      for (int r = 0; r < 2; ++r)
#pragma unroll
        for (int j = 0; j < 4; ++j) {
          float v = acc[r][c][j] + bv[c];
          if (RELU) v = fmaxf(v, 0.f);
          Lf[wr + r * 16 + kg * 4 + j][col] = v;
        }
    }
    __syncthreads();
#pragma unroll
    for (int i = 0; i < 8; ++i) {
      int s = tid + 256 * i;              // 2048 slots of 16B (64 rows x 32)
      int rr = s >> 5, cc = (s & 31) * 4;
      int gr = rowBase + rr;
      if (gr < M)
        *reinterpret_cast<float4*>(&outF[(size_t)gr * ldOut + colBase + cc]) =
            *reinterpret_cast<const float4*>(&Lf[rr][cc]);
    }
  }
}

// ---------------- conversions ----------------
__global__ void cvt_x_k(const float* __restrict__ x, f16* __restrict__ xf, int n) {
  int i = (blockIdx.x * 256 + threadIdx.x) * 4;
  if (i < n) {
    float4 v = *reinterpret_cast<const float4*>(&x[i]);
    xf[i] = (f16)v.x; xf[i + 1] = (f16)v.y; xf[i + 2] = (f16)v.z; xf[i + 3] = (f16)v.w;
  }
}

// fused pre weight: Wt[256][128]; col n<128 -> W_pre[k][n] (C), n>=128 -> W_pre[128+k][n-128] (P2)
__global__ void prep_wpre_k(const float* __restrict__ W, f16* __restrict__ Wt) {
  int e = blockIdx.x * 256 + threadIdx.x;
  if (e < 256 * 128) {
    int n = e >> 7, k = e & 127;
    float v = (n < 128) ? W[(size_t)k * 128 + n] : W[(size_t)(128 + k) * 128 + (n - 128)];
    Wt[e] = (f16)v;
  }
}

// generic: W [K][128] -> Wt f16 [128][K]
__global__ void transp_w_k(const float* __restrict__ W, f16* __restrict__ Wt, int K) {
  int e = blockIdx.x * 256 + threadIdx.x;
  if (e < 128 * K) {
    int nn = e / K, kk = e - nn * K;
    Wt[e] = (f16)W[(size_t)kk * 128 + nn];
  }
}

// ---------------- CSR build ----------------
__global__ void zero_k(int* __restrict__ p, int n) {
  int i = blockIdx.x * 256 + threadIdx.x;
  if (i < n) p[i] = 0;
}

__global__ void count_k(const int* __restrict__ ei, int* __restrict__ deg, int E) {
  int e = blockIdx.x * 256 + threadIdx.x;
  if (e < E) atomicAdd(&deg[ei[E + e]], 1);
}

__device__ __forceinline__ int blockExclScan(int v, int* wtot) {
  int lane = threadIdx.x & 63, wid = threadIdx.x >> 6;
  int x = v;
#pragma unroll
  for (int d = 1; d < 64; d <<= 1) {
    int y = __shfl_up(x, d);
    if (lane >= d) x += y;
  }
  if (lane == 63) wtot[wid] = x;
  __syncthreads();
  if (threadIdx.x == 0) {
    int s = 0;
#pragma unroll
    for (int k = 0; k < 4; ++k) { int t = wtot[k]; wtot[k] = s; s += t; }
  }
  __syncthreads();
  return wtot[wid] + x - v;
}

__global__ __launch_bounds__(256) void scan1_k(const int* __restrict__ deg,
                                               int* __restrict__ offs,
                                               int* __restrict__ partials, int n) {
  __shared__ int wtot[4];
  int i = blockIdx.x * 256 + threadIdx.x;
  int v = (i < n) ? deg[i] : 0;
  int e = blockExclScan(v, wtot);
  if (i < n) offs[i] = e;
  if (threadIdx.x == 255) partials[blockIdx.x] = e + v;
}

__global__ __launch_bounds__(256) void scan2_k(int* __restrict__ partials, int nb) {
  __shared__ int wtot[4];
  int v = (threadIdx.x < nb) ? partials[threadIdx.x] : 0;
  int e = blockExclScan(v, wtot);
  if (threadIdx.x < nb) partials[threadIdx.x] = e;
}

__global__ void scan3_k(const int* __restrict__ partials, int* __restrict__ offs,
                        int* __restrict__ cur, int n, int E) {
  int i = blockIdx.x * 256 + threadIdx.x;
  if (i < n) {
    int v = offs[i] + partials[i >> 8];
    offs[i] = v; cur[i] = v;
  }
  if (i == 0) offs[n] = E;
}

__global__ void scatter_k(const int* __restrict__ ei, int* __restrict__ cursor,
                          int* __restrict__ ssrc, int E) {
  int e = blockIdx.x * 256 + threadIdx.x;
  if (e < E) {
    int d = ei[E + e];
    int pos = atomicAdd(&cursor[d], 1);
    ssrc[pos] = ei[e];
  }
}

// ---------------- aggregation: one WAVE per node, lane t owns cols {2t,2t+1} ----------------
__global__ __launch_bounds__(256) void agg_k(
    const f16* __restrict__ CP, const int* __restrict__ offs,
    const int* __restrict__ ssrc, f16* __restrict__ AGG, int N)
{
  int w = threadIdx.x >> 6;
  int t = threadIdx.x & 63;
  int i = blockIdx.x * 4 + w;
  if (i >= N) return;
  int start = offs[i], end = offs[i + 1];
  int deg = end - start;
  unsigned* AGGu = (unsigned*)AGG;              // 256 uints per row
  size_t o = (size_t)i * 256 + t;
  if (deg == 0) {
    AGGu[o] = 0u; AGGu[o + 64] = 0u; AGGu[o + 128] = 0u; AGGu[o + 192] = 0u;
    return;
  }
  const unsigned* CPu = (const unsigned*)CP;    // 128 uints per row; P2 half at +64
  float s0 = 0.f, s1 = 0.f, q0 = 0.f, q1 = 0.f;
  float mx0 = -INFINITY, mx1 = -INFINITY, mn0 = INFINITY, mn1 = INFINITY;
  for (int base = start; base < end; base += 64) {
    int cnt = min(end - base, 64);
    int myidx = (base + t < end) ? ssrc[base + t] : 0;
    for (int j = 0; j < cnt; ++j) {
      int src = __shfl(myidx, j);
      float2 v = unpackh2(CPu[(size_t)src * 128 + 64 + t]);
      s0 += v.x; s1 += v.y;
      q0 += v.x * v.x; q1 += v.y * v.y;
      mx0 = fmaxf(mx0, v.x); mx1 = fmaxf(mx1, v.y);
      mn0 = fminf(mn0, v.x); mn1 = fminf(mn1, v.y);
    }
  }
  float2 c = unpackh2(CPu[(size_t)i * 128 + t]);
  float degf = (float)deg;
  float inv = 1.f / degf;
  float m10 = s0 * inv, m11 = s1 * inv;
  float var0 = fmaxf(q0 * inv - m10 * m10, 0.f);
  float var1 = fmaxf(q1 * inv - m11 * m11, 0.f);
  float sd0 = sqrtf(var0 + 1e-5f), sd1 = sqrtf(var1 + 1e-5f);
  float sc = degf * (1.0f / 16.0f);             // deg / avg_deg, avg_deg = 16 exactly
  AGGu[o]       = packh2((c.x + m10) * sc, (c.y + m11) * sc);
  AGGu[o + 64]  = packh2((c.x + mx0) * sc, (c.y + mx1) * sc);
  AGGu[o + 128] = packh2((c.x + mn0) * sc, (c.y + mn1) * sc);
  AGGu[o + 192] = packh2(sd0 * sc, sd1 * sc);
}

extern "C" void kernel_launch(void* const* d_in, const int* in_sizes, int n_in,
                              void* d_out, int out_size, void* d_ws, size_t ws_size,
                              hipStream_t stream) {
  const float* x      = (const float*)d_in[0];
  const float* W_pre  = (const float*)d_in[1];
  const float* b_pre  = (const float*)d_in[2];
  const float* W_post = (const float*)d_in[3];
  const float* b_post = (const float*)d_in[4];
  const float* W_lin  = (const float*)d_in[5];
  const float* b_lin  = (const float*)d_in[6];
  const int*   ei     = (const int*)d_in[7];

  const int N = in_sizes[0] / 128;
  const int E = in_sizes[7] / 2;

  char* ws = (char*)d_ws;
  size_t off = 0;
  auto alloc = [&](size_t bytes) -> void* {
    void* p = ws + off; off += (bytes + 255) & ~(size_t)255; return p;
  };
  f16*   xf     = (f16*)  alloc((size_t)N * 128 * 2);
  f16*   CP     = (f16*)  alloc((size_t)N * 256 * 2);   // [C | P2]
  f16*   AGG    = (f16*)  alloc((size_t)N * 512 * 2);
  f16*   T1     = (f16*)  alloc((size_t)N * 128 * 2);
  f16*   WtPre  = (f16*)  alloc(256 * 128 * 2);
  f16*   WtPost = (f16*)  alloc(128 * 640 * 2);
  f16*   WtLin  = (f16*)  alloc(128 * 128 * 2);
  int*   ssrc   = (int*)  alloc((size_t)E * 4);
  int*   deg    = (int*)  alloc((size_t)N * 4);
  int*   offs   = (int*)  alloc((size_t)(N + 1) * 4);
  int*   cur    = (int*)  alloc((size_t)N * 4);
  int*   parts  = (int*)  alloc(1024 * 4);

  const int gTile = (N + 63) / 64;          // 782 row tiles
  const int gE    = (E + 255) / 256;
  const int gN    = (N + 255) / 256;        // 196 scan blocks

  // conversions / weight prep
  cvt_x_k<<<(N * 128 / 4 + 255) / 256, 256, 0, stream>>>(x, xf, N * 128);
  prep_wpre_k<<<(256 * 128 + 255) / 256, 256, 0, stream>>>(W_pre, WtPre);
  transp_w_k<<<(128 * 640 + 255) / 256, 256, 0, stream>>>(W_post, WtPost, 640);
  transp_w_k<<<(128 * 128 + 255) / 256, 256, 0, stream>>>(W_lin,  WtLin,  128);

  zero_k<<<gN, 256, 0, stream>>>(deg, N);

  // fused pre GEMM: CP[N][256] = x @ [WpreT|WpreB]  (bias only on first 128 cols)
  gemm_reg_k<128, 128, true, false, true><<<dim3(gTile, 2), 256, 0, stream>>>(
      xf, nullptr, WtPre, b_pre, nullptr, CP, N, 256);

  // CSR build by dst
  count_k<<<gE, 256, 0, stream>>>(ei, deg, E);
  scan1_k<<<gN, 256, 0, stream>>>(deg, offs, parts, N);
  scan2_k<<<1, 256, 0, stream>>>(parts, gN);
  scan3_k<<<gN, 256, 0, stream>>>(parts, offs, cur, N, E);
  scatter_k<<<gE, 256, 0, stream>>>(ei, cur, ssrc, E);

  // aggregation -> AGG f16 [N][512]
  agg_k<<<(N + 3) / 4, 256, 0, stream>>>(CP, offs, ssrc, AGG, N);

  // post MLP: T1 = concat(x, AGG) @ W_post + b_post   (f16 out)
  gemm_reg_k<640, 128, true, false, true><<<dim3(gTile, 1), 256, 0, stream>>>(
      xf, AGG, WtPost, b_post, nullptr, T1, N, 128);
  // final: out = relu(T1 @ W_lin + b_lin)   (f32 out)
  gemm_reg_k<128, 128, true, true, false><<<dim3(gTile, 1), 256, 0, stream>>>(
      T1, nullptr, WtLin, b_lin, (float*)d_out, nullptr, N, 128);
}

// Round 8
// 312.683 us; speedup vs baseline: 2.0589x; 1.1130x over previous
//
#include <hip/hip_runtime.h>
#include <hip/hip_bf16.h>
#include <math.h>

// PNA forward (round 6 kernel, resubmit after 2x infra failures):
//   CP = x @ [W_preT | W_preB] + [b_pre|0]   f16 [N][256]  (C | P2)
//   per dst i: h_e = C[i] + P2[src]; mean/max/min shift by c, var shift-invariant
//   AGG f16 [N][512] = [mean,max,min,std] * deg/16   (avg_deg = E/N = 16 exactly)
//   W_comb = W_post @ W_lin (folded on device: no nonlinearity between them)
//   out f32 = relu(concat(x, AGG) @ W_comb + b_comb)

typedef _Float16 f16;
typedef _Float16 f16x8 __attribute__((ext_vector_type(8)));
typedef _Float16 f16x2 __attribute__((ext_vector_type(2)));
typedef float    f32x4 __attribute__((ext_vector_type(4)));

__device__ __forceinline__ unsigned packh2(float a, float b) {
  union { unsigned u; f16x2 h; } x; x.h = (f16x2){(f16)a, (f16)b}; return x.u;
}
__device__ __forceinline__ float2 unpackh2(unsigned v) {
  union { unsigned u; f16x2 h; } x; x.u = v;
  return make_float2((float)x.h.x, (float)x.h.y);
}

// ---------------- register-fragment MFMA GEMM (no LDS staging, no K-loop barriers) ----------------
// out[M, *] = concat(A1[:,KO1], A2) @ Wt^T + bias.  Wt: f16 [NCOL][KTOT] (transposed weights).
// Block 256 thr / 4 waves; tile 64 rows x 128 cols; wave tile 32x64 (2x4 16x16 frags).
// Fragments straight global->VGPR (weights L2-resident), 2-deep reg pipeline.
// LDS only for the coalesced epilogue.
template<int KTOT, int KO1, bool HASB, bool RELU, bool OUTF16>
__global__ __launch_bounds__(256) void gemm_reg_k(
    const f16* __restrict__ A1, const f16* __restrict__ A2,
    const f16* __restrict__ Wt, const float* __restrict__ bias,
    float* __restrict__ outF, f16* __restrict__ outH, int M, int ldOut)
{
  const int tid = threadIdx.x;
  const int l   = tid & 63;
  const int w   = tid >> 6;
  const int wr  = (w >> 1) * 32;
  const int wc  = (w & 1) * 64;
  const int li  = l & 15, kg = l >> 4;
  const int rowBase = blockIdx.x * 64;
  const int colBase = blockIdx.y * 128;
  constexpr int ld2 = (KTOT > KO1) ? (KTOT - KO1) : 1;

  int aOff[2], a2Off[2], bOff[4];
#pragma unroll
  for (int r = 0; r < 2; ++r) {
    int gr = rowBase + wr + r * 16 + li; if (gr > M - 1) gr = M - 1;
    aOff[r] = gr * KO1; a2Off[r] = gr * ld2;
  }
#pragma unroll
  for (int c = 0; c < 4; ++c) bOff[c] = (colBase + wc + c * 16 + li) * KTOT;

  f32x4 acc[2][4];
#pragma unroll
  for (int r = 0; r < 2; ++r)
#pragma unroll
    for (int c = 0; c < 4; ++c) acc[r][c] = (f32x4){0.f, 0.f, 0.f, 0.f};

  f16x8 aA[2], bA[4], aB[2], bB[4];
  auto lf = [&](int k0, f16x8 a[2], f16x8 b[4]) {
    int k = k0 + kg * 8;
    if (KO1 == KTOT || k0 < KO1) {      // wave-uniform (steps never straddle KO1)
#pragma unroll
      for (int r = 0; r < 2; ++r) a[r] = *reinterpret_cast<const f16x8*>(A1 + aOff[r] + k);
    } else {
#pragma unroll
      for (int r = 0; r < 2; ++r) a[r] = *reinterpret_cast<const f16x8*>(A2 + a2Off[r] + (k - KO1));
    }
#pragma unroll
    for (int c = 0; c < 4; ++c) b[c] = *reinterpret_cast<const f16x8*>(Wt + bOff[c] + k);
  };

  lf(0, aA, bA);
  for (int k0 = 0; k0 < KTOT; k0 += 64) {
    lf(k0 + 32, aB, bB);
#pragma unroll
    for (int r = 0; r < 2; ++r)
#pragma unroll
      for (int c = 0; c < 4; ++c)
        acc[r][c] = __builtin_amdgcn_mfma_f32_16x16x32_f16(aA[r], bA[c], acc[r][c], 0, 0, 0);
    if (k0 + 64 < KTOT) lf(k0 + 64, aA, bA);
#pragma unroll
    for (int r = 0; r < 2; ++r)
#pragma unroll
      for (int c = 0; c < 4; ++c)
        acc[r][c] = __builtin_amdgcn_mfma_f32_16x16x32_f16(aB[r], bB[c], acc[r][c], 0, 0, 0);
  }

  float bv[4];
#pragma unroll
  for (int c = 0; c < 4; ++c) {
    int col = colBase + wc + c * 16 + li;
    bv[c] = (HASB && col < 128) ? bias[col] : 0.f;
  }

  // epilogue: C/D layout col = li, row = kg*4 + j [HW-verified]; LDS bounce -> coalesced stores
  if constexpr (OUTF16) {
    __shared__ __align__(16) f16 Ls[64][136];
#pragma unroll
    for (int c = 0; c < 4; ++c) {
      int col = wc + c * 16 + li;
#pragma unroll
      for (int r = 0; r < 2; ++r)
#pragma unroll
        for (int j = 0; j < 4; ++j) {
          float v = acc[r][c][j] + bv[c];
          if (RELU) v = fmaxf(v, 0.f);
          Ls[wr + r * 16 + kg * 4 + j][col] = (f16)v;
        }
    }
    __syncthreads();
#pragma unroll
    for (int i = 0; i < 4; ++i) {
      int s = tid + 256 * i;
      int rr = s >> 4, cc = (s & 15) * 8;
      int gr = rowBase + rr;
      if (gr < M)
        *reinterpret_cast<float4*>(&outH[(size_t)gr * ldOut + colBase + cc]) =
            *reinterpret_cast<const float4*>(&Ls[rr][cc]);
    }
  } else {
    __shared__ __align__(16) float Lf[64][132];
#pragma unroll
    for (int c = 0; c < 4; ++c) {
      int col = wc + c * 16 + li;
#pragma unroll
      for (int r = 0; r < 2; ++r)
#pragma unroll
        for (int j = 0; j < 4; ++j) {
          float v = acc[r][c][j] + bv[c];
          if (RELU) v = fmaxf(v, 0.f);
          Lf[wr + r * 16 + kg * 4 + j][col] = v;
        }
    }
    __syncthreads();
#pragma unroll
    for (int i = 0; i < 8; ++i) {
      int s = tid + 256 * i;
      int rr = s >> 5, cc = (s & 31) * 4;
      int gr = rowBase + rr;
      if (gr < M)
        *reinterpret_cast<float4*>(&outF[(size_t)gr * ldOut + colBase + cc]) =
            *reinterpret_cast<const float4*>(&Lf[rr][cc]);
    }
  }
}

// ---------------- conversions / weight prep ----------------
__global__ void cvt_x_k(const float* __restrict__ x, f16* __restrict__ xf, int n) {
  int i = (blockIdx.x * 256 + threadIdx.x) * 4;
  if (i < n) {
    float4 v = *reinterpret_cast<const float4*>(&x[i]);
    xf[i] = (f16)v.x; xf[i + 1] = (f16)v.y; xf[i + 2] = (f16)v.z; xf[i + 3] = (f16)v.w;
  }
}

// fused pre weight: Wt[256][128]; col n<128 -> W_pre[k][n] (C), n>=128 -> W_pre[128+k][n-128] (P2)
__global__ void prep_wpre_k(const float* __restrict__ W, f16* __restrict__ Wt) {
  int e = blockIdx.x * 256 + threadIdx.x;
  if (e < 256 * 128) {
    int n = e >> 7, k = e & 127;
    float v = (n < 128) ? W[(size_t)k * 128 + n] : W[(size_t)(128 + k) * 128 + (n - 128)];
    Wt[e] = (f16)v;
  }
}

// fold: WtComb[n][k] = sum_m W_post[k][m]*W_lin[m][n]  (f16, transposed layout [128][640])
//       bcomb[n]    = sum_m b_post[m]*W_lin[m][n] + b_lin[n]
__global__ void fold_w_k(const float* __restrict__ Wpost, const float* __restrict__ bpost,
                         const float* __restrict__ Wlin,  const float* __restrict__ blin,
                         f16* __restrict__ WtComb, float* __restrict__ bcomb) {
  int e = blockIdx.x * 256 + threadIdx.x;
  if (e < 640 * 128) {
    int n = e / 640, k = e - n * 640;
    float s = 0.f;
#pragma unroll 4
    for (int m = 0; m < 128; ++m) s += Wpost[(size_t)k * 128 + m] * Wlin[(size_t)m * 128 + n];
    WtComb[(size_t)n * 640 + k] = (f16)s;
  } else if (e < 640 * 128 + 128) {
    int n = e - 640 * 128;
    float s = blin[n];
#pragma unroll 4
    for (int m = 0; m < 128; ++m) s += bpost[m] * Wlin[(size_t)m * 128 + n];
    bcomb[n] = s;
  }
}

// ---------------- CSR build ----------------
__global__ void zero_k(int* __restrict__ p, int n) {
  int i = blockIdx.x * 256 + threadIdx.x;
  if (i < n) p[i] = 0;
}

__global__ void count_k(const int* __restrict__ ei, int* __restrict__ deg, int E) {
  int e = blockIdx.x * 256 + threadIdx.x;
  if (e < E) atomicAdd(&deg[ei[E + e]], 1);
}

__device__ __forceinline__ int blockExclScan(int v, int* wtot) {
  int lane = threadIdx.x & 63, wid = threadIdx.x >> 6;
  int x = v;
#pragma unroll
  for (int d = 1; d < 64; d <<= 1) {
    int y = __shfl_up(x, d);
    if (lane >= d) x += y;
  }
  if (lane == 63) wtot[wid] = x;
  __syncthreads();
  if (threadIdx.x == 0) {
    int s = 0;
#pragma unroll
    for (int k = 0; k < 4; ++k) { int t = wtot[k]; wtot[k] = s; s += t; }
  }
  __syncthreads();
  return wtot[wid] + x - v;
}

__global__ __launch_bounds__(256) void scan1_k(const int* __restrict__ deg,
                                               int* __restrict__ offs,
                                               int* __restrict__ partials, int n) {
  __shared__ int wtot[4];
  int i = blockIdx.x * 256 + threadIdx.x;
  int v = (i < n) ? deg[i] : 0;
  int e = blockExclScan(v, wtot);
  if (i < n) offs[i] = e;
  if (threadIdx.x == 255) partials[blockIdx.x] = e + v;
}

__global__ __launch_bounds__(256) void scan2_k(int* __restrict__ partials, int nb) {
  __shared__ int wtot[4];
  int v = (threadIdx.x < nb) ? partials[threadIdx.x] : 0;
  int e = blockExclScan(v, wtot);
  if (threadIdx.x < nb) partials[threadIdx.x] = e;
}

__global__ void scan3_k(const int* __restrict__ partials, int* __restrict__ offs,
                        int* __restrict__ cur, int n, int E) {
  int i = blockIdx.x * 256 + threadIdx.x;
  if (i < n) {
    int v = offs[i] + partials[i >> 8];
    offs[i] = v; cur[i] = v;
  }
  if (i == 0) offs[n] = E;
}

__global__ void scatter_k(const int* __restrict__ ei, int* __restrict__ cursor,
                          int* __restrict__ ssrc, int E) {
  int e = blockIdx.x * 256 + threadIdx.x;
  if (e < E) {
    int d = ei[E + e];
    int pos = atomicAdd(&cursor[d], 1);
    ssrc[pos] = ei[e];
  }
}

// ---------------- aggregation: one WAVE per node, lane t owns cols {2t,2t+1} ----------------
// 4x unrolled gather: 4 independent loads in flight per wave (breaks serial latency chain).
__global__ __launch_bounds__(256) void agg_k(
    const f16* __restrict__ CP, const int* __restrict__ offs,
    const int* __restrict__ ssrc, f16* __restrict__ AGG, int N)
{
  int w = threadIdx.x >> 6;
  int t = threadIdx.x & 63;
  int i = blockIdx.x * 4 + w;
  if (i >= N) return;
  int start = offs[i], end = offs[i + 1];
  int deg = end - start;
  unsigned* AGGu = (unsigned*)AGG;              // 256 uints per row
  size_t o = (size_t)i * 256 + t;
  if (deg == 0) {
    AGGu[o] = 0u; AGGu[o + 64] = 0u; AGGu[o + 128] = 0u; AGGu[o + 192] = 0u;
    return;
  }
  const unsigned* CPu = (const unsigned*)CP;    // 128 uints per row; P2 half at +64
  float s0 = 0.f, s1 = 0.f, q0 = 0.f, q1 = 0.f;
  float mx0 = -INFINITY, mx1 = -INFINITY, mn0 = INFINITY, mn1 = INFINITY;

  auto accum = [&](unsigned u) {
    float2 v = unpackh2(u);
    s0 += v.x; s1 += v.y;
    q0 = fmaf(v.x, v.x, q0); q1 = fmaf(v.y, v.y, q1);
    mx0 = fmaxf(mx0, v.x); mx1 = fmaxf(mx1, v.y);
    mn0 = fminf(mn0, v.x); mn1 = fminf(mn1, v.y);
  };

  for (int base = start; base < end; base += 64) {
    int cnt = min(end - base, 64);
    int myoff = 0;
    if (base + t < end) myoff = ssrc[base + t] * 128 + 64;   // prescaled uint-row offset of P2
    int j = 0;
    for (; j + 4 <= cnt; j += 4) {
      int o0 = __shfl(myoff, j);
      int o1 = __shfl(myoff, j + 1);
      int o2 = __shfl(myoff, j + 2);
      int o3 = __shfl(myoff, j + 3);
      unsigned u0 = CPu[o0 + t];
      unsigned u1 = CPu[o1 + t];
      unsigned u2 = CPu[o2 + t];
      unsigned u3 = CPu[o3 + t];
      accum(u0); accum(u1); accum(u2); accum(u3);
    }
    for (; j < cnt; ++j) {
      int o0 = __shfl(myoff, j);
      accum(CPu[o0 + t]);
    }
  }

  float2 c = unpackh2(CPu[(size_t)i * 128 + t]);
  float degf = (float)deg;
  float inv = 1.f / degf;
  float m10 = s0 * inv, m11 = s1 * inv;
  float var0 = fmaxf(q0 * inv - m10 * m10, 0.f);
  float var1 = fmaxf(q1 * inv - m11 * m11, 0.f);
  float sd0 = sqrtf(var0 + 1e-5f), sd1 = sqrtf(var1 + 1e-5f);
  float sc = degf * (1.0f / 16.0f);             // deg / avg_deg, avg_deg = 16 exactly
  AGGu[o]       = packh2((c.x + m10) * sc, (c.y + m11) * sc);
  AGGu[o + 64]  = packh2((c.x + mx0) * sc, (c.y + mx1) * sc);
  AGGu[o + 128] = packh2((c.x + mn0) * sc, (c.y + mn1) * sc);
  AGGu[o + 192] = packh2(sd0 * sc, sd1 * sc);
}

extern "C" void kernel_launch(void* const* d_in, const int* in_sizes, int n_in,
                              void* d_out, int out_size, void* d_ws, size_t ws_size,
                              hipStream_t stream) {
  const float* x      = (const float*)d_in[0];
  const float* W_pre  = (const float*)d_in[1];
  const float* b_pre  = (const float*)d_in[2];
  const float* W_post = (const float*)d_in[3];
  const float* b_post = (const float*)d_in[4];
  const float* W_lin  = (const float*)d_in[5];
  const float* b_lin  = (const float*)d_in[6];
  const int*   ei     = (const int*)d_in[7];

  const int N = in_sizes[0] / 128;
  const int E = in_sizes[7] / 2;

  char* ws = (char*)d_ws;
  size_t off = 0;
  auto alloc = [&](size_t bytes) -> void* {
    void* p = ws + off; off += (bytes + 255) & ~(size_t)255; return p;
  };
  f16*   xf     = (f16*)  alloc((size_t)N * 128 * 2);
  f16*   CP     = (f16*)  alloc((size_t)N * 256 * 2);   // [C | P2]
  f16*   AGG    = (f16*)  alloc((size_t)N * 512 * 2);
  f16*   WtPre  = (f16*)  alloc(256 * 128 * 2);
  f16*   WtComb = (f16*)  alloc(128 * 640 * 2);
  float* bcomb  = (float*)alloc(128 * 4);
  int*   ssrc   = (int*)  alloc((size_t)E * 4);
  int*   deg    = (int*)  alloc((size_t)N * 4);
  int*   offs   = (int*)  alloc((size_t)(N + 1) * 4);
  int*   cur    = (int*)  alloc((size_t)N * 4);
  int*   parts  = (int*)  alloc(1024 * 4);

  const int gTile = (N + 63) / 64;          // 782 row tiles
  const int gE    = (E + 255) / 256;
  const int gN    = (N + 255) / 256;        // 196 scan blocks

  // conversions / weight prep
  cvt_x_k<<<(N * 128 / 4 + 255) / 256, 256, 0, stream>>>(x, xf, N * 128);
  prep_wpre_k<<<(256 * 128 + 255) / 256, 256, 0, stream>>>(W_pre, WtPre);
  fold_w_k<<<(640 * 128 + 128 + 255) / 256, 256, 0, stream>>>(W_post, b_post, W_lin, b_lin, WtComb, bcomb);

  zero_k<<<gN, 256, 0, stream>>>(deg, N);

  // fused pre GEMM: CP[N][256] = x @ [WpreT|WpreB]  (bias only on first 128 cols)
  gemm_reg_k<128, 128, true, false, true><<<dim3(gTile, 2), 256, 0, stream>>>(
      xf, nullptr, WtPre, b_pre, nullptr, CP, N, 256);

  // CSR build by dst
  count_k<<<gE, 256, 0, stream>>>(ei, deg, E);
  scan1_k<<<gN, 256, 0, stream>>>(deg, offs, parts, N);
  scan2_k<<<1, 256, 0, stream>>>(parts, gN);
  scan3_k<<<gN, 256, 0, stream>>>(parts, offs, cur, N, E);
  scatter_k<<<gE, 256, 0, stream>>>(ei, cur, ssrc, E);

  // aggregation -> AGG f16 [N][512]
  agg_k<<<(N + 3) / 4, 256, 0, stream>>>(CP, offs, ssrc, AGG, N);

  // folded post MLP: out = relu(concat(x, AGG) @ W_comb + b_comb)   (f32 out)
  gemm_reg_k<640, 128, true, true, false><<<dim3(gTile, 1), 256, 0, stream>>>(
      xf, AGG, WtComb, bcomb, (float*)d_out, nullptr, N, 128);
}